// Round 10
// baseline (138.758 us; speedup 1.0000x reference)
//
#include <hip/hip_runtime.h>
#include <math.h>

#define PI_F 3.14159265358979323846f

typedef _Float16 half2_t __attribute__((ext_vector_type(2)));

__device__ __forceinline__ unsigned packh2(float lo, float hi) {
  unsigned short l = __builtin_bit_cast(unsigned short, (_Float16)lo);
  unsigned short h = __builtin_bit_cast(unsigned short, (_Float16)hi);
  return (unsigned)l | ((unsigned)h << 16);
}

struct c2 { float x, y; };
__device__ __forceinline__ c2 cmul(c2 a, c2 b){ return c2{a.x*b.x - a.y*b.y, a.x*b.y + a.y*b.x}; }
__device__ __forceinline__ c2 cadd(c2 a, c2 b){ return c2{a.x+b.x, a.y+b.y}; }

__device__ __forceinline__ void rot2(c2 &a, c2 &b, c2 g00, c2 g01, c2 g10, c2 g11) {
  c2 na = cadd(cmul(g00,a), cmul(g01,b));
  c2 nb = cadd(cmul(g10,a), cmul(g11,b));
  a = na; b = nb;
}

__device__ __forceinline__ void mk_u3(float th, float ph, float la,
                                      c2 &g00, c2 &g01, c2 &g10, c2 &g11) {
  float ch = cosf(0.5f*th), sh = sinf(0.5f*th);
  float cl = cosf(la), sl = sinf(la);
  float cp = cosf(ph), sp = sinf(ph);
  float cpl = cp*cl - sp*sl, spl = sp*cl + cp*sl;
  g00 = c2{ch, 0.f};
  g01 = c2{-cl*sh, -sl*sh};
  g10 = c2{cp*sh, sp*sh};
  g11 = c2{cpl*ch, spl*ch};
}

template<int MA, int MB>
__device__ __forceinline__ void apply2q(c2 psi[16], const c2 M[16]) {
#pragma unroll
  for (int r = 0; r < 16; ++r) {
    if (r & (MA | MB)) continue;
    c2 a = psi[r], b = psi[r|MB], c = psi[r|MA], d = psi[r|MA|MB];
    psi[r]        = cadd(cadd(cmul(M[0],a),  cmul(M[1],b)),  cadd(cmul(M[2],c),  cmul(M[3],d)));
    psi[r|MB]     = cadd(cadd(cmul(M[4],a),  cmul(M[5],b)),  cadd(cmul(M[6],c),  cmul(M[7],d)));
    psi[r|MA]     = cadd(cadd(cmul(M[8],a),  cmul(M[9],b)),  cadd(cmul(M[10],c), cmul(M[11],d)));
    psi[r|MA|MB]  = cadd(cadd(cmul(M[12],a), cmul(M[13],b)), cadd(cmul(M[14],c), cmul(M[15],d)));
  }
}

// ---------------- K0: build A_w = Re(U^dag Z_w U), 4 x 16 x 16 ----------------
__global__ __launch_bounds__(256) void k_qmat(const float* __restrict__ qw_u3,
                                              const float* __restrict__ qw_ang,
                                              float* __restrict__ A) {
  __shared__ c2 SU[2][16];
  __shared__ float Ur[16*17], Ui[16*17];
  int t = threadIdx.x;
  if (t < 8) {
    int L = t >> 2, col = t & 3;
    c2 s[4];
#pragma unroll
    for (int i = 0; i < 4; ++i) s[i] = c2{(i==col)?1.f:0.f, 0.f};
    const float* u = qw_u3 + 12*L;
    const float* g = qw_ang + 3*L;
    c2 g00,g01,g10,g11;
    mk_u3(u[0],u[1],u[2], g00,g01,g10,g11);             // u3s[0] on a (mask 2)
    rot2(s[0],s[2], g00,g01,g10,g11); rot2(s[1],s[3], g00,g01,g10,g11);
    mk_u3(u[3],u[4],u[5], g00,g01,g10,g11);             // u3s[1] on b (mask 1)
    rot2(s[0],s[1], g00,g01,g10,g11); rot2(s[2],s[3], g00,g01,g10,g11);
    { c2 tmp = s[2]; s[2] = s[3]; s[3] = tmp; }          // CNOT a->b
    { float c = cosf(0.5f*g[0]), sn = sinf(0.5f*g[0]);
      c2 r00{c,0.f}, r01{-sn,0.f}, r10{sn,0.f}, r11{c,0.f};
      rot2(s[0],s[2], r00,r01,r10,r11); rot2(s[1],s[3], r00,r01,r10,r11); } // RY on a
    { float c = cosf(0.5f*g[1]), sn = sinf(0.5f*g[1]);
      c2 e0{c,-sn}, e1{c,sn};
      s[0]=cmul(s[0],e0); s[1]=cmul(s[1],e1); s[2]=cmul(s[2],e0); s[3]=cmul(s[3],e1); } // RZ on b
    { c2 tmp = s[1]; s[1] = s[3]; s[3] = tmp; }          // CNOT b->a
    { float c = cosf(0.5f*g[2]), sn = sinf(0.5f*g[2]);
      c2 r00{c,0.f}, r01{-sn,0.f}, r10{sn,0.f}, r11{c,0.f};
      rot2(s[0],s[2], r00,r01,r10,r11); rot2(s[1],s[3], r00,r01,r10,r11); } // RY on a
    { c2 tmp = s[2]; s[2] = s[3]; s[3] = tmp; }          // CNOT a->b
    mk_u3(u[6],u[7],u[8], g00,g01,g10,g11);             // u3s[2] on a
    rot2(s[0],s[2], g00,g01,g10,g11); rot2(s[1],s[3], g00,g01,g10,g11);
    mk_u3(u[9],u[10],u[11], g00,g01,g10,g11);           // u3s[3] on b
    rot2(s[0],s[1], g00,g01,g10,g11); rot2(s[2],s[3], g00,g01,g10,g11);
#pragma unroll
    for (int k = 0; k < 4; ++k) SU[L][k*4 + col] = s[k];
  }
  __syncthreads();
  if (t < 16) {
    c2 psi[16];
#pragma unroll
    for (int i = 0; i < 16; ++i) psi[i] = c2{(i==t)?1.f:0.f, 0.f};
#pragma unroll
    for (int l = 0; l < 2; ++l) {
      c2 M[16];
#pragma unroll
      for (int k = 0; k < 16; ++k) M[k] = SU[l][k];
      apply2q<8,4>(psi, M);   // pair (0,1)
      apply2q<4,2>(psi, M);   // pair (1,2)
      apply2q<2,1>(psi, M);   // pair (2,3)
      apply2q<1,8>(psi, M);   // pair (3,0)
    }
#pragma unroll
    for (int k = 0; k < 16; ++k) { Ur[k*17+t] = psi[k].x; Ui[k*17+t] = psi[k].y; }
  }
  __syncthreads();
  {
    int i = t >> 4, j = t & 15;
    float a0=0.f,a1=0.f,a2=0.f,a3=0.f;
#pragma unroll
    for (int k = 0; k < 16; ++k) {
      float pr = Ur[k*17+i]*Ur[k*17+j] + Ui[k*17+i]*Ui[k*17+j];
      a0 += ((k>>3)&1) ? -pr : pr;
      a1 += ((k>>2)&1) ? -pr : pr;
      a2 += ((k>>1)&1) ? -pr : pr;
      a3 += ( k     &1) ? -pr : pr;
    }
    A[0*256 + t] = a0; A[1*256 + t] = a1; A[2*256 + t] = a2; A[3*256 + t] = a3;
  }
}

// ------- Ktrans: transpose FC weights + pack conv2 weights to f16 pairs -------
// w2p layout: [32 icpair][16 oc][9] u32, u32 = (f16 w[oc][p], f16 w[oc][p+32])
__global__ __launch_bounds__(256) void k_trans(const float* __restrict__ w1a, const float* __restrict__ w1b,
                                               const float* __restrict__ w2a, const float* __restrict__ w2b,
                                               const float* __restrict__ c2w, float* __restrict__ wt) {
  int id = blockIdx.x*256 + threadIdx.x;
  if (id < 16384) { int j = id >> 6, o = id & 63;  wt[id] = w1a[o*256 + j]; return; }
  int id1 = id - 16384;
  if (id1 < 8192)  { int j = id1 >> 7, o = id1 & 127; wt[16384 + id1] = w1b[o*64 + j]; return; }
  int id2 = id1 - 8192;
  if (id2 < 8192)  { int j = id2 >> 6, o = id2 & 63;  wt[24576 + id2] = w2a[o*128 + j]; return; }
  int id3 = id2 - 8192;
  if (id3 < 640)   { int j = id3 / 10, o = id3 % 10;  wt[32768 + id3] = w2b[o*64 + j]; return; }
  int id4 = id3 - 640;
  if (id4 < 4608) {
    int p = id4 / 144, rr = id4 - p*144;
    int oc = rr / 9, k = rr - oc*9;
    float lo = c2w[oc*576 + p*9 + k];
    float hi = c2w[oc*576 + (p+32)*9 + k];
    ((unsigned*)wt)[33408 + id4] = packh2(lo, hi);
  }
}

// ---- K1: conv1(3->64)+relu+pool, v2: oc-half split for occupancy. ----
// Block (b, oh): pairs oh*16 .. oh*16+15. fp32 compute, h1 f16-packed (oc,oc+32)
// identical to v1 => bit-identical downstream.
__global__ __launch_bounds__(256) void k_conv1(const float* __restrict__ x, const float* __restrict__ w,
                                               const float* __restrict__ bias, unsigned* __restrict__ h1p) {
  __shared__ float xs[3*32*32];
  int bid = blockIdx.x, b = bid >> 1, oh = bid & 1, tid = threadIdx.x;
  const float4* xsrc = (const float4*)(x + (size_t)b*3072);
  float4* xd = (float4*)xs;
#pragma unroll
  for (int k = 0; k < 3; ++k) xd[tid + k*256] = xsrc[tid + k*256];
  __syncthreads();
  int y = tid >> 4, xo = tid & 15;
  int y2 = y*2, x2 = xo*2;
  float in[3][4][4];
#pragma unroll
  for (int c = 0; c < 3; ++c)
#pragma unroll
    for (int ky = 0; ky < 4; ++ky) {
      int iy = y2 + ky - 1;
      bool vy = ((unsigned)iy < 32u);
      int iyc = vy ? iy : 0;
#pragma unroll
      for (int kx = 0; kx < 4; ++kx) {
        int ix = x2 + kx - 1;
        bool v = vy && ((unsigned)ix < 32u);
        int ixc = ((unsigned)ix < 32u) ? ix : 0;
        float val = xs[c*1024 + iyc*32 + ixc];
        in[c][ky][kx] = v ? val : 0.f;
      }
    }
  unsigned* outp = h1p + (size_t)b*8192 + tid;
  int p0 = oh*16;
  for (int pi = 0; pi < 16; ++pi) {
    int p = p0 + pi;
    const float* wpa = w + p*27;
    const float* wpb = w + (p+32)*27;
    float ba = bias[p], bb = bias[p+32];
    float a00=ba, a01=ba, a10=ba, a11=ba;
    float c00=bb, c01=bb, c10=bb, c11=bb;
#pragma unroll
    for (int c = 0; c < 3; ++c)
#pragma unroll
      for (int ky = 0; ky < 3; ++ky)
#pragma unroll
        for (int kx = 0; kx < 3; ++kx) {
          float wa = wpa[c*9 + ky*3 + kx];
          float wb = wpb[c*9 + ky*3 + kx];
          float i00 = in[c][ky  ][kx  ], i01 = in[c][ky  ][kx+1];
          float i10 = in[c][ky+1][kx  ], i11 = in[c][ky+1][kx+1];
          a00 = fmaf(wa, i00, a00); a01 = fmaf(wa, i01, a01);
          a10 = fmaf(wa, i10, a10); a11 = fmaf(wa, i11, a11);
          c00 = fmaf(wb, i00, c00); c01 = fmaf(wb, i01, c01);
          c10 = fmaf(wb, i10, c10); c11 = fmaf(wb, i11, c11);
        }
    float ma = fmaxf(fmaxf(fmaxf(a00,a01), fmaxf(a10,a11)), 0.f);
    float mb = fmaxf(fmaxf(fmaxf(c00,c01), fmaxf(c10,c11)), 0.f);
    outp[p*256] = packh2(ma, mb);
  }
}

// ---- K2: conv2(64->16)+relu+pool, v7: half-image blocks for occupancy. ----
// LDS [32 pair][10 rows][24 u32] = 30720 B -> 5 blocks/CU. Reads stride 24
// (== 8 mod 32), lanes 4r x 16x -> every bank exactly 2 lanes, conflict-free.
__global__ __launch_bounds__(256) void k_conv2(const unsigned* __restrict__ h1p,
                                               const unsigned* __restrict__ w2p,
                                               const float* __restrict__ bias, float* __restrict__ h2) {
  __shared__ unsigned hsp[32*10*24];   // 7680 u32 = 30720 B
  int bid = blockIdx.x, b = bid >> 1, h = bid & 1, t = threadIdx.x;
  {
    uint4 z = make_uint4(0u,0u,0u,0u);
    uint4* hz = (uint4*)hsp;
    for (int i = t; i < 1920; i += 256) hz[i] = z;
  }
  __syncthreads();
  // stage 9 valid rows: local row = row9 + (1-h), global row g = 7*h + row9
  const uint4* src = (const uint4*)(h1p + (size_t)b*8192);   // [32 pair][16 rows][4 uint4]
#pragma unroll
  for (int k = 0; k < 5; ++k) {
    int idx = t + k*256;               // 0..1151
    if (idx < 1152) {
      int p = idx / 36, rem = idx - p*36;
      int row9 = rem >> 2, c4 = rem & 3;
      uint4 v = src[p*64 + (7*h + row9)*4 + c4];
      unsigned* d = &hsp[p*240 + (row9 + 1 - h)*24 + 1 + c4*4];
      d[0]=v.x; d[1]=v.y; d[2]=v.z; d[3]=v.w;
    }
  }
  __syncthreads();
  int ocg = __builtin_amdgcn_readfirstlane((int)(t >> 7));   // wave-uniform
  int pos = t & 127;
  int yl = pos >> 4, x = pos & 15;     // conv row yl (0..7) within this half
  float acc[8];
#pragma unroll
  for (int o = 0; o < 8; ++o) acc[o] = bias[ocg*8 + o];
#pragma unroll 2
  for (int p = 0; p < 32; ++p) {
    unsigned in9[9];
#pragma unroll
    for (int dy = 0; dy < 3; ++dy)
#pragma unroll
      for (int kx = 0; kx < 3; ++kx)
        in9[dy*3+kx] = hsp[p*240 + (yl+dy)*24 + x + kx];
    const unsigned* wp = w2p + p*144 + ocg*72;   // wave-uniform -> s_load
#pragma unroll
    for (int o = 0; o < 8; ++o)
#pragma unroll
      for (int k9 = 0; k9 < 9; ++k9)
        acc[o] = __builtin_amdgcn_fdot2(__builtin_bit_cast(half2_t, in9[k9]),
                                        __builtin_bit_cast(half2_t, wp[o*9+k9]),
                                        acc[o], false);
  }
  // 2x2 maxpool: x^1 via lane^1, yl^1 via lane^16; relu + write
  bool writer = ((yl & 1) == 0) && ((x & 1) == 0);
  int py = h*4 + (yl >> 1), px = x >> 1;
  float* outb = h2 + (size_t)b*1024;
#pragma unroll
  for (int o = 0; o < 8; ++o) {
    float m = fmaxf(acc[o], __shfl_xor(acc[o], 1, 64));
    m = fmaxf(m, __shfl_xor(m, 16, 64));
    if (writer) outb[(ocg*8+o)*64 + py*8 + px] = fmaxf(m, 0.f);
  }
}

// ---- K3: conv3(16->4)+leaky+sigmoid*pi -> quantum quadratic forms (fused) ----
__global__ __launch_bounds__(256) void k_conv3q(const float* __restrict__ h2, const float* __restrict__ w,
                                                const float* __restrict__ bias, const float* __restrict__ Ag,
                                                float* __restrict__ q) {
  __shared__ float S[4*1600 + 1024];
  float* h3s = S;                      // 4 imgs x [16][10][10] zero-padded
  float* As  = S + 6400;               // [4][256]
  int b4 = blockIdx.x*4, t = threadIdx.x;
#pragma unroll
  for (int k = 0; k < 4; ++k) As[t + k*256] = Ag[t + k*256];
  for (int i = t; i < 6400; i += 256) h3s[i] = 0.f;
  __syncthreads();
  int img = t >> 6, lane = t & 63;
  const float4* src = (const float4*)(h2 + (size_t)(b4+img)*1024);
#pragma unroll
  for (int k = 0; k < 4; ++k) {
    float4 v = src[lane + k*64];
    int e = 4*(lane + k*64);
    int ic = e >> 6, iy = (e >> 3) & 7, ix = e & 7;
    float* d = &h3s[img*1600 + ic*100 + (iy+1)*10 + ix + 1];
    d[0]=v.x; d[1]=v.y; d[2]=v.z; d[3]=v.w;
  }
  __syncthreads();
  int y = lane >> 3, xo = lane & 7;
  float acc[4];
#pragma unroll
  for (int o = 0; o < 4; ++o) acc[o] = bias[o];
  for (int ic = 0; ic < 16; ++ic) {
    float in[3][3];
#pragma unroll
    for (int ky = 0; ky < 3; ++ky)
#pragma unroll
      for (int kx = 0; kx < 3; ++kx)
        in[ky][kx] = h3s[img*1600 + ic*100 + (y+ky)*10 + (xo+kx)];
#pragma unroll
    for (int o = 0; o < 4; ++o) {
      const float* wp = w + (o*16 + ic)*9;
#pragma unroll
      for (int ky = 0; ky < 3; ++ky)
#pragma unroll
        for (int kx = 0; kx < 3; ++kx)
          acc[o] = fmaf(wp[ky*3+kx], in[ky][kx], acc[o]);
    }
  }
  float v0[2], v1[2], v2[2], v3[2];
#pragma unroll
  for (int o = 0; o < 4; ++o) {
    float v = acc[o];
    float l = v > 0.f ? v : 0.01f*v;
    float sg = 1.f/(1.f + expf(-l));
    float sv, cv;
    __sincosf(sg * (0.5f*PI_F), &sv, &cv);
    float* dst = (o==0)?v0:(o==1)?v1:(o==2)?v2:v3;
    dst[0] = cv; dst[1] = sv;
  }
  float pv[16];
#pragma unroll
  for (int i = 0; i < 16; ++i)
    pv[i] = v0[(i>>3)&1] * v1[(i>>2)&1] * v2[(i>>1)&1] * v3[i&1];
  float ev[4];
#pragma unroll
  for (int w4 = 0; w4 < 4; ++w4) {
    const float4* Aw = (const float4*)(As + w4*256);
    float a = 0.f;
#pragma unroll
    for (int i = 0; i < 16; ++i) {
      float d = 0.f;
#pragma unroll
      for (int j4 = 0; j4 < 4; ++j4) {
        float4 av = Aw[i*4 + j4];
        d = fmaf(av.x, pv[j4*4+0], d);
        d = fmaf(av.y, pv[j4*4+1], d);
        d = fmaf(av.z, pv[j4*4+2], d);
        d = fmaf(av.w, pv[j4*4+3], d);
      }
      a = fmaf(pv[i], d, a);
    }
    ev[w4] = a;
  }
  size_t p = (size_t)(b4+img)*64 + lane;
  ((float4*)q)[p] = make_float4(ev[0], ev[1], ev[2], ev[3]);
}

// ---------------- K5: fused FC chain, one wave per batch row ----------------
__global__ __launch_bounds__(256) void k_fc(const float* __restrict__ q, const float* __restrict__ wt,
                                            const float* __restrict__ b1a, const float* __restrict__ b1b,
                                            const float* __restrict__ b2a, const float* __restrict__ b2b,
                                            float* __restrict__ out) {
  __shared__ float sh[4][512];
  int tid = threadIdx.x, wv = tid >> 6, lane = tid & 63;
  int row = blockIdx.x*4 + wv;
  float* S = sh[wv];
  const float4* qr = (const float4*)(q + (size_t)row*256);
  ((float4*)S)[lane] = qr[lane];
  __syncthreads();
  const float* WT1a = wt;
  const float* WT1b = wt + 16384;
  const float* WT2a = wt + 24576;
  const float* WT2b = wt + 32768;
  float acc = b1a[lane];
  for (int j = 0; j < 256; ++j) acc = fmaf(WT1a[j*64+lane], S[j], acc);
  float h = fmaxf(acc, 0.f);
  __syncthreads();
  S[256+lane] = h;
  __syncthreads();
  float a0 = b1b[lane], a1 = b1b[64+lane];
  for (int j = 0; j < 64; ++j) {
    float sj = S[256+j];
    a0 = fmaf(WT1b[j*128+lane],    sj, a0);
    a1 = fmaf(WT1b[j*128+64+lane], sj, a1);
  }
  __syncthreads();
  S[320+lane] = a0; S[384+lane] = a1;
  __syncthreads();
  float c2a = b2a[lane];
  for (int j = 0; j < 128; ++j) c2a = fmaf(WT2a[j*64+lane], S[320+j], c2a);
  float h2v = fmaxf(c2a, 0.f);
  __syncthreads();
  S[448+lane] = h2v;
  __syncthreads();
  if (lane < 10) {
    float o = b2b[lane];
    for (int j = 0; j < 64; ++j) o = fmaf(WT2b[j*10+lane], S[448+j], o);
    out[(size_t)row*10 + lane] = o;
  }
}

extern "C" void kernel_launch(void* const* d_in, const int* in_sizes, int n_in,
                              void* d_out, int out_size, void* d_ws, size_t ws_size,
                              hipStream_t stream) {
  const float* x       = (const float*)d_in[0];
  const float* conv1_w = (const float*)d_in[1];
  const float* conv1_b = (const float*)d_in[2];
  const float* conv2_w = (const float*)d_in[3];
  const float* conv2_b = (const float*)d_in[4];
  const float* conv3_w = (const float*)d_in[5];
  const float* conv3_b = (const float*)d_in[6];
  const float* qw_u3   = (const float*)d_in[7];
  const float* qw_ang  = (const float*)d_in[8];
  const float* fc1a_w  = (const float*)d_in[9];
  const float* fc1a_b  = (const float*)d_in[10];
  const float* fc1b_w  = (const float*)d_in[11];
  const float* fc1b_b  = (const float*)d_in[12];
  const float* fc2a_w  = (const float*)d_in[13];
  const float* fc2a_b  = (const float*)d_in[14];
  const float* fc2b_w  = (const float*)d_in[15];
  const float* fc2b_b  = (const float*)d_in[16];
  float* out = (float*)d_out;

  float* ws  = (float*)d_ws;
  float* A   = ws;                      // 1024 floats
  float* WT  = ws + 1024;               // fc transposes (33408 f32) + packed conv2 (4608 u32)
  const unsigned* W2P = (const unsigned*)(WT + 33408);
  float* q   = ws + 43648;              // 262144 floats (1024x256)
  unsigned* h1p = (unsigned*)(ws + 305792);  // 8388608 u32 (1024 x 32pair x 16 x 16)
  float* h2  = ws + 17083008;           // 1048576 floats  (1024x16x8x8)

  k_qmat  <<<1,    256, 0, stream>>>(qw_u3, qw_ang, A);
  k_trans <<<167,  256, 0, stream>>>(fc1a_w, fc1b_w, fc2a_w, fc2b_w, conv2_w, WT);
  k_conv1 <<<2048, 256, 0, stream>>>(x, conv1_w, conv1_b, h1p);
  k_conv2 <<<2048, 256, 0, stream>>>(h1p, W2P, conv2_b, h2);
  k_conv3q<<<256,  256, 0, stream>>>(h2, conv3_w, conv3_b, A, q);
  k_fc    <<<256,  256, 0, stream>>>(q, WT, fc1a_b, fc1b_b, fc2a_b, fc2b_b, out);
}

// Round 11
// 127.240 us; speedup vs baseline: 1.0905x; 1.0905x over previous
//
#include <hip/hip_runtime.h>
#include <math.h>

#define PI_F 3.14159265358979323846f

typedef _Float16 half2_t __attribute__((ext_vector_type(2)));

__device__ __forceinline__ unsigned packh2(float lo, float hi) {
  unsigned short l = __builtin_bit_cast(unsigned short, (_Float16)lo);
  unsigned short h = __builtin_bit_cast(unsigned short, (_Float16)hi);
  return (unsigned)l | ((unsigned)h << 16);
}

struct c2 { float x, y; };
__device__ __forceinline__ c2 cmul(c2 a, c2 b){ return c2{a.x*b.x - a.y*b.y, a.x*b.y + a.y*b.x}; }
__device__ __forceinline__ c2 cadd(c2 a, c2 b){ return c2{a.x+b.x, a.y+b.y}; }

__device__ __forceinline__ void rot2(c2 &a, c2 &b, c2 g00, c2 g01, c2 g10, c2 g11) {
  c2 na = cadd(cmul(g00,a), cmul(g01,b));
  c2 nb = cadd(cmul(g10,a), cmul(g11,b));
  a = na; b = nb;
}

__device__ __forceinline__ void mk_u3(float th, float ph, float la,
                                      c2 &g00, c2 &g01, c2 &g10, c2 &g11) {
  float ch = cosf(0.5f*th), sh = sinf(0.5f*th);
  float cl = cosf(la), sl = sinf(la);
  float cp = cosf(ph), sp = sinf(ph);
  float cpl = cp*cl - sp*sl, spl = sp*cl + cp*sl;
  g00 = c2{ch, 0.f};
  g01 = c2{-cl*sh, -sl*sh};
  g10 = c2{cp*sh, sp*sh};
  g11 = c2{cpl*ch, spl*ch};
}

template<int MA, int MB>
__device__ __forceinline__ void apply2q(c2 psi[16], const c2 M[16]) {
#pragma unroll
  for (int r = 0; r < 16; ++r) {
    if (r & (MA | MB)) continue;
    c2 a = psi[r], b = psi[r|MB], c = psi[r|MA], d = psi[r|MA|MB];
    psi[r]        = cadd(cadd(cmul(M[0],a),  cmul(M[1],b)),  cadd(cmul(M[2],c),  cmul(M[3],d)));
    psi[r|MB]     = cadd(cadd(cmul(M[4],a),  cmul(M[5],b)),  cadd(cmul(M[6],c),  cmul(M[7],d)));
    psi[r|MA]     = cadd(cadd(cmul(M[8],a),  cmul(M[9],b)),  cadd(cmul(M[10],c), cmul(M[11],d)));
    psi[r|MA|MB]  = cadd(cadd(cmul(M[12],a), cmul(M[13],b)), cadd(cmul(M[14],c), cmul(M[15],d)));
  }
}

// ---------------- K0: build A_w = Re(U^dag Z_w U), 4 x 16 x 16 ----------------
__global__ __launch_bounds__(256) void k_qmat(const float* __restrict__ qw_u3,
                                              const float* __restrict__ qw_ang,
                                              float* __restrict__ A) {
  __shared__ c2 SU[2][16];
  __shared__ float Ur[16*17], Ui[16*17];
  int t = threadIdx.x;
  if (t < 8) {
    int L = t >> 2, col = t & 3;
    c2 s[4];
#pragma unroll
    for (int i = 0; i < 4; ++i) s[i] = c2{(i==col)?1.f:0.f, 0.f};
    const float* u = qw_u3 + 12*L;
    const float* g = qw_ang + 3*L;
    c2 g00,g01,g10,g11;
    mk_u3(u[0],u[1],u[2], g00,g01,g10,g11);             // u3s[0] on a (mask 2)
    rot2(s[0],s[2], g00,g01,g10,g11); rot2(s[1],s[3], g00,g01,g10,g11);
    mk_u3(u[3],u[4],u[5], g00,g01,g10,g11);             // u3s[1] on b (mask 1)
    rot2(s[0],s[1], g00,g01,g10,g11); rot2(s[2],s[3], g00,g01,g10,g11);
    { c2 tmp = s[2]; s[2] = s[3]; s[3] = tmp; }          // CNOT a->b
    { float c = cosf(0.5f*g[0]), sn = sinf(0.5f*g[0]);
      c2 r00{c,0.f}, r01{-sn,0.f}, r10{sn,0.f}, r11{c,0.f};
      rot2(s[0],s[2], r00,r01,r10,r11); rot2(s[1],s[3], r00,r01,r10,r11); } // RY on a
    { float c = cosf(0.5f*g[1]), sn = sinf(0.5f*g[1]);
      c2 e0{c,-sn}, e1{c,sn};
      s[0]=cmul(s[0],e0); s[1]=cmul(s[1],e1); s[2]=cmul(s[2],e0); s[3]=cmul(s[3],e1); } // RZ on b
    { c2 tmp = s[1]; s[1] = s[3]; s[3] = tmp; }          // CNOT b->a
    { float c = cosf(0.5f*g[2]), sn = sinf(0.5f*g[2]);
      c2 r00{c,0.f}, r01{-sn,0.f}, r10{sn,0.f}, r11{c,0.f};
      rot2(s[0],s[2], r00,r01,r10,r11); rot2(s[1],s[3], r00,r01,r10,r11); } // RY on a
    { c2 tmp = s[2]; s[2] = s[3]; s[3] = tmp; }          // CNOT a->b
    mk_u3(u[6],u[7],u[8], g00,g01,g10,g11);             // u3s[2] on a
    rot2(s[0],s[2], g00,g01,g10,g11); rot2(s[1],s[3], g00,g01,g10,g11);
    mk_u3(u[9],u[10],u[11], g00,g01,g10,g11);           // u3s[3] on b
    rot2(s[0],s[1], g00,g01,g10,g11); rot2(s[2],s[3], g00,g01,g10,g11);
#pragma unroll
    for (int k = 0; k < 4; ++k) SU[L][k*4 + col] = s[k];
  }
  __syncthreads();
  if (t < 16) {
    c2 psi[16];
#pragma unroll
    for (int i = 0; i < 16; ++i) psi[i] = c2{(i==t)?1.f:0.f, 0.f};
#pragma unroll
    for (int l = 0; l < 2; ++l) {
      c2 M[16];
#pragma unroll
      for (int k = 0; k < 16; ++k) M[k] = SU[l][k];
      apply2q<8,4>(psi, M);   // pair (0,1)
      apply2q<4,2>(psi, M);   // pair (1,2)
      apply2q<2,1>(psi, M);   // pair (2,3)
      apply2q<1,8>(psi, M);   // pair (3,0)
    }
#pragma unroll
    for (int k = 0; k < 16; ++k) { Ur[k*17+t] = psi[k].x; Ui[k*17+t] = psi[k].y; }
  }
  __syncthreads();
  {
    int i = t >> 4, j = t & 15;
    float a0=0.f,a1=0.f,a2=0.f,a3=0.f;
#pragma unroll
    for (int k = 0; k < 16; ++k) {
      float pr = Ur[k*17+i]*Ur[k*17+j] + Ui[k*17+i]*Ui[k*17+j];
      a0 += ((k>>3)&1) ? -pr : pr;
      a1 += ((k>>2)&1) ? -pr : pr;
      a2 += ((k>>1)&1) ? -pr : pr;
      a3 += ( k     &1) ? -pr : pr;
    }
    A[0*256 + t] = a0; A[1*256 + t] = a1; A[2*256 + t] = a2; A[3*256 + t] = a3;
  }
}

// ------- Ktrans: FC transposes + conv2 f16 pack + conv1 f16 pack (13 pairs + w26 + bias) -------
__global__ __launch_bounds__(256) void k_trans(const float* __restrict__ w1a, const float* __restrict__ w1b,
                                               const float* __restrict__ w2a, const float* __restrict__ w2b,
                                               const float* __restrict__ c2w,
                                               const float* __restrict__ c1w, const float* __restrict__ c1b,
                                               float* __restrict__ wt) {
  int id = blockIdx.x*256 + threadIdx.x;
  if (id < 16384) { int j = id >> 6, o = id & 63;  wt[id] = w1a[o*256 + j]; return; }
  int id1 = id - 16384;
  if (id1 < 8192)  { int j = id1 >> 7, o = id1 & 127; wt[16384 + id1] = w1b[o*64 + j]; return; }
  int id2 = id1 - 8192;
  if (id2 < 8192)  { int j = id2 >> 6, o = id2 & 63;  wt[24576 + id2] = w2a[o*128 + j]; return; }
  int id3 = id2 - 8192;
  if (id3 < 640)   { int j = id3 / 10, o = id3 % 10;  wt[32768 + id3] = w2b[o*64 + j]; return; }
  int id4 = id3 - 640;
  if (id4 < 4608) {
    int p = id4 / 144, rr = id4 - p*144;
    int oc = rr / 9, k = rr - oc*9;
    float lo = c2w[oc*576 + p*9 + k];
    float hi = c2w[oc*576 + (p+32)*9 + k];
    ((unsigned*)wt)[33408 + id4] = packh2(lo, hi);
    return;
  }
  int id5 = id4 - 4608;
  if (id5 < 1024) {
    int oc = id5 >> 4, s = id5 & 15;
    unsigned v;
    if (s < 13)      v = packh2(c1w[oc*27 + 2*s], c1w[oc*27 + 2*s + 1]);
    else if (s == 13) v = __builtin_bit_cast(unsigned, c1w[oc*27 + 26]);
    else if (s == 14) v = __builtin_bit_cast(unsigned, c1b[oc]);
    else             v = 0u;
    ((unsigned*)wt)[38016 + id5] = v;
  }
}

// ---- K1: conv1(3->64)+relu+pool, v3: f16 fdot2 (13 pairs + 1 fp32 leftover). ----
// Block (b, oh): pairs oh*16..oh*16+15. Windows packed once/thread, reused 16x.
__global__ __launch_bounds__(256) void k_conv1(const float* __restrict__ x,
                                               const unsigned* __restrict__ w1p,
                                               unsigned* __restrict__ h1p) {
  __shared__ float xs[3*32*32];
  int bid = blockIdx.x, b = bid >> 1, oh = bid & 1, tid = threadIdx.x;
  const float4* xsrc = (const float4*)(x + (size_t)b*3072);
  float4* xd = (float4*)xs;
#pragma unroll
  for (int k = 0; k < 3; ++k) xd[tid + k*256] = xsrc[tid + k*256];
  __syncthreads();
  int y = tid >> 4, xo = tid & 15;
  int y2 = y*2, x2 = xo*2;
  float in[3][4][4];
#pragma unroll
  for (int c = 0; c < 3; ++c)
#pragma unroll
    for (int ky = 0; ky < 4; ++ky) {
      int iy = y2 + ky - 1;
      bool vy = ((unsigned)iy < 32u);
      int iyc = vy ? iy : 0;
#pragma unroll
      for (int kx = 0; kx < 4; ++kx) {
        int ix = x2 + kx - 1;
        bool v = vy && ((unsigned)ix < 32u);
        int ixc = ((unsigned)ix < 32u) ? ix : 0;
        float val = xs[c*1024 + iyc*32 + ixc];
        in[c][ky][kx] = v ? val : 0.f;
      }
    }
  // pack the 4 conv-position windows: 13 half2 pairs + 1 fp32 leftover each
  half2_t pk[4][13];
  float l26[4];
#pragma unroll
  for (int pos = 0; pos < 4; ++pos) {
    int dy = pos >> 1, dx = pos & 1;
#pragma unroll
    for (int i = 0; i < 13; ++i) {
      int e0 = 2*i, e1 = 2*i + 1;
      float v0 = in[e0/9][(e0%9)/3 + dy][e0%3 + dx];
      float v1 = in[e1/9][(e1%9)/3 + dy][e1%3 + dx];
      pk[pos][i] = __builtin_bit_cast(half2_t, packh2(v0, v1));
    }
    l26[pos] = in[2][2+dy][2+dx];
  }
  unsigned* outp = h1p + (size_t)b*8192 + tid;
  int p0 = oh*16;
  for (int pi = 0; pi < 16; ++pi) {
    int p = p0 + pi;
    const unsigned* wa = w1p + p*16;        // wave-uniform -> s_load
    const unsigned* wb = w1p + (p+32)*16;
    float ba = __builtin_bit_cast(float, wa[14]);
    float bb = __builtin_bit_cast(float, wb[14]);
    float A0=ba, A1=ba, A2=ba, A3=ba;
    float C0=bb, C1=bb, C2=bb, C3=bb;
#pragma unroll
    for (int i = 0; i < 13; ++i) {
      half2_t wha = __builtin_bit_cast(half2_t, wa[i]);
      half2_t whb = __builtin_bit_cast(half2_t, wb[i]);
      A0 = __builtin_amdgcn_fdot2(pk[0][i], wha, A0, false);
      A1 = __builtin_amdgcn_fdot2(pk[1][i], wha, A1, false);
      A2 = __builtin_amdgcn_fdot2(pk[2][i], wha, A2, false);
      A3 = __builtin_amdgcn_fdot2(pk[3][i], wha, A3, false);
      C0 = __builtin_amdgcn_fdot2(pk[0][i], whb, C0, false);
      C1 = __builtin_amdgcn_fdot2(pk[1][i], whb, C1, false);
      C2 = __builtin_amdgcn_fdot2(pk[2][i], whb, C2, false);
      C3 = __builtin_amdgcn_fdot2(pk[3][i], whb, C3, false);
    }
    float w26a = __builtin_bit_cast(float, wa[13]);
    float w26b = __builtin_bit_cast(float, wb[13]);
    A0 = fmaf(w26a, l26[0], A0); A1 = fmaf(w26a, l26[1], A1);
    A2 = fmaf(w26a, l26[2], A2); A3 = fmaf(w26a, l26[3], A3);
    C0 = fmaf(w26b, l26[0], C0); C1 = fmaf(w26b, l26[1], C1);
    C2 = fmaf(w26b, l26[2], C2); C3 = fmaf(w26b, l26[3], C3);
    float ma = fmaxf(fmaxf(fmaxf(A0,A1), fmaxf(A2,A3)), 0.f);
    float mb = fmaxf(fmaxf(fmaxf(C0,C1), fmaxf(C2,C3)), 0.f);
    outp[p*256] = packh2(ma, mb);
  }
}

// ---- K2: conv2(64->16)+relu+pool, v7: half-image blocks for occupancy. ----
// LDS [32 pair][10 rows][24 u32] = 30720 B -> 5 blocks/CU. Reads stride 24
// (== 8 mod 32), lanes 4r x 16x -> every bank exactly 2 lanes, conflict-free.
__global__ __launch_bounds__(256) void k_conv2(const unsigned* __restrict__ h1p,
                                               const unsigned* __restrict__ w2p,
                                               const float* __restrict__ bias, float* __restrict__ h2) {
  __shared__ unsigned hsp[32*10*24];   // 7680 u32 = 30720 B
  int bid = blockIdx.x, b = bid >> 1, h = bid & 1, t = threadIdx.x;
  {
    uint4 z = make_uint4(0u,0u,0u,0u);
    uint4* hz = (uint4*)hsp;
    for (int i = t; i < 1920; i += 256) hz[i] = z;
  }
  __syncthreads();
  // stage 9 valid rows: local row = row9 + (1-h), global row g = 7*h + row9
  const uint4* src = (const uint4*)(h1p + (size_t)b*8192);   // [32 pair][16 rows][4 uint4]
#pragma unroll
  for (int k = 0; k < 5; ++k) {
    int idx = t + k*256;               // 0..1151
    if (idx < 1152) {
      int p = idx / 36, rem = idx - p*36;
      int row9 = rem >> 2, c4 = rem & 3;
      uint4 v = src[p*64 + (7*h + row9)*4 + c4];
      unsigned* d = &hsp[p*240 + (row9 + 1 - h)*24 + 1 + c4*4];
      d[0]=v.x; d[1]=v.y; d[2]=v.z; d[3]=v.w;
    }
  }
  __syncthreads();
  int ocg = __builtin_amdgcn_readfirstlane((int)(t >> 7));   // wave-uniform
  int pos = t & 127;
  int yl = pos >> 4, x = pos & 15;     // conv row yl (0..7) within this half
  float acc[8];
#pragma unroll
  for (int o = 0; o < 8; ++o) acc[o] = bias[ocg*8 + o];
#pragma unroll 2
  for (int p = 0; p < 32; ++p) {
    unsigned in9[9];
#pragma unroll
    for (int dy = 0; dy < 3; ++dy)
#pragma unroll
      for (int kx = 0; kx < 3; ++kx)
        in9[dy*3+kx] = hsp[p*240 + (yl+dy)*24 + x + kx];
    const unsigned* wp = w2p + p*144 + ocg*72;   // wave-uniform -> s_load
#pragma unroll
    for (int o = 0; o < 8; ++o)
#pragma unroll
      for (int k9 = 0; k9 < 9; ++k9)
        acc[o] = __builtin_amdgcn_fdot2(__builtin_bit_cast(half2_t, in9[k9]),
                                        __builtin_bit_cast(half2_t, wp[o*9+k9]),
                                        acc[o], false);
  }
  // 2x2 maxpool: x^1 via lane^1, yl^1 via lane^16; relu + write
  bool writer = ((yl & 1) == 0) && ((x & 1) == 0);
  int py = h*4 + (yl >> 1), px = x >> 1;
  float* outb = h2 + (size_t)b*1024;
#pragma unroll
  for (int o = 0; o < 8; ++o) {
    float m = fmaxf(acc[o], __shfl_xor(acc[o], 1, 64));
    m = fmaxf(m, __shfl_xor(m, 16, 64));
    if (writer) outb[(ocg*8+o)*64 + py*8 + px] = fmaxf(m, 0.f);
  }
}

// ---- K3: conv3(16->4)+leaky+sigmoid*pi -> quantum quadratic forms (fused) ----
__global__ __launch_bounds__(256) void k_conv3q(const float* __restrict__ h2, const float* __restrict__ w,
                                                const float* __restrict__ bias, const float* __restrict__ Ag,
                                                float* __restrict__ q) {
  __shared__ float S[4*1600 + 1024];
  float* h3s = S;                      // 4 imgs x [16][10][10] zero-padded
  float* As  = S + 6400;               // [4][256]
  int b4 = blockIdx.x*4, t = threadIdx.x;
#pragma unroll
  for (int k = 0; k < 4; ++k) As[t + k*256] = Ag[t + k*256];
  for (int i = t; i < 6400; i += 256) h3s[i] = 0.f;
  __syncthreads();
  int img = t >> 6, lane = t & 63;
  const float4* src = (const float4*)(h2 + (size_t)(b4+img)*1024);
#pragma unroll
  for (int k = 0; k < 4; ++k) {
    float4 v = src[lane + k*64];
    int e = 4*(lane + k*64);
    int ic = e >> 6, iy = (e >> 3) & 7, ix = e & 7;
    float* d = &h3s[img*1600 + ic*100 + (iy+1)*10 + ix + 1];
    d[0]=v.x; d[1]=v.y; d[2]=v.z; d[3]=v.w;
  }
  __syncthreads();
  int y = lane >> 3, xo = lane & 7;
  float acc[4];
#pragma unroll
  for (int o = 0; o < 4; ++o) acc[o] = bias[o];
  for (int ic = 0; ic < 16; ++ic) {
    float in[3][3];
#pragma unroll
    for (int ky = 0; ky < 3; ++ky)
#pragma unroll
      for (int kx = 0; kx < 3; ++kx)
        in[ky][kx] = h3s[img*1600 + ic*100 + (y+ky)*10 + (xo+kx)];
#pragma unroll
    for (int o = 0; o < 4; ++o) {
      const float* wp = w + (o*16 + ic)*9;
#pragma unroll
      for (int ky = 0; ky < 3; ++ky)
#pragma unroll
        for (int kx = 0; kx < 3; ++kx)
          acc[o] = fmaf(wp[ky*3+kx], in[ky][kx], acc[o]);
    }
  }
  float v0[2], v1[2], v2[2], v3[2];
#pragma unroll
  for (int o = 0; o < 4; ++o) {
    float v = acc[o];
    float l = v > 0.f ? v : 0.01f*v;
    float sg = 1.f/(1.f + expf(-l));
    float sv, cv;
    __sincosf(sg * (0.5f*PI_F), &sv, &cv);
    float* dst = (o==0)?v0:(o==1)?v1:(o==2)?v2:v3;
    dst[0] = cv; dst[1] = sv;
  }
  float pv[16];
#pragma unroll
  for (int i = 0; i < 16; ++i)
    pv[i] = v0[(i>>3)&1] * v1[(i>>2)&1] * v2[(i>>1)&1] * v3[i&1];
  float ev[4];
#pragma unroll
  for (int w4 = 0; w4 < 4; ++w4) {
    const float4* Aw = (const float4*)(As + w4*256);
    float a = 0.f;
#pragma unroll
    for (int i = 0; i < 16; ++i) {
      float d = 0.f;
#pragma unroll
      for (int j4 = 0; j4 < 4; ++j4) {
        float4 av = Aw[i*4 + j4];
        d = fmaf(av.x, pv[j4*4+0], d);
        d = fmaf(av.y, pv[j4*4+1], d);
        d = fmaf(av.z, pv[j4*4+2], d);
        d = fmaf(av.w, pv[j4*4+3], d);
      }
      a = fmaf(pv[i], d, a);
    }
    ev[w4] = a;
  }
  size_t p = (size_t)(b4+img)*64 + lane;
  ((float4*)q)[p] = make_float4(ev[0], ev[1], ev[2], ev[3]);
}

// ---------------- K5: fused FC chain, one wave per batch row ----------------
__global__ __launch_bounds__(256) void k_fc(const float* __restrict__ q, const float* __restrict__ wt,
                                            const float* __restrict__ b1a, const float* __restrict__ b1b,
                                            const float* __restrict__ b2a, const float* __restrict__ b2b,
                                            float* __restrict__ out) {
  __shared__ float sh[4][512];
  int tid = threadIdx.x, wv = tid >> 6, lane = tid & 63;
  int row = blockIdx.x*4 + wv;
  float* S = sh[wv];
  const float4* qr = (const float4*)(q + (size_t)row*256);
  ((float4*)S)[lane] = qr[lane];
  __syncthreads();
  const float* WT1a = wt;
  const float* WT1b = wt + 16384;
  const float* WT2a = wt + 24576;
  const float* WT2b = wt + 32768;
  float acc = b1a[lane];
  for (int j = 0; j < 256; ++j) acc = fmaf(WT1a[j*64+lane], S[j], acc);
  float h = fmaxf(acc, 0.f);
  __syncthreads();
  S[256+lane] = h;
  __syncthreads();
  float a0 = b1b[lane], a1 = b1b[64+lane];
  for (int j = 0; j < 64; ++j) {
    float sj = S[256+j];
    a0 = fmaf(WT1b[j*128+lane],    sj, a0);
    a1 = fmaf(WT1b[j*128+64+lane], sj, a1);
  }
  __syncthreads();
  S[320+lane] = a0; S[384+lane] = a1;
  __syncthreads();
  float c2a = b2a[lane];
  for (int j = 0; j < 128; ++j) c2a = fmaf(WT2a[j*64+lane], S[320+j], c2a);
  float h2v = fmaxf(c2a, 0.f);
  __syncthreads();
  S[448+lane] = h2v;
  __syncthreads();
  if (lane < 10) {
    float o = b2b[lane];
    for (int j = 0; j < 64; ++j) o = fmaf(WT2b[j*10+lane], S[448+j], o);
    out[(size_t)row*10 + lane] = o;
  }
}

extern "C" void kernel_launch(void* const* d_in, const int* in_sizes, int n_in,
                              void* d_out, int out_size, void* d_ws, size_t ws_size,
                              hipStream_t stream) {
  const float* x       = (const float*)d_in[0];
  const float* conv1_w = (const float*)d_in[1];
  const float* conv1_b = (const float*)d_in[2];
  const float* conv2_w = (const float*)d_in[3];
  const float* conv2_b = (const float*)d_in[4];
  const float* conv3_w = (const float*)d_in[5];
  const float* conv3_b = (const float*)d_in[6];
  const float* qw_u3   = (const float*)d_in[7];
  const float* qw_ang  = (const float*)d_in[8];
  const float* fc1a_w  = (const float*)d_in[9];
  const float* fc1a_b  = (const float*)d_in[10];
  const float* fc1b_w  = (const float*)d_in[11];
  const float* fc1b_b  = (const float*)d_in[12];
  const float* fc2a_w  = (const float*)d_in[13];
  const float* fc2a_b  = (const float*)d_in[14];
  const float* fc2b_w  = (const float*)d_in[15];
  const float* fc2b_b  = (const float*)d_in[16];
  float* out = (float*)d_out;

  float* ws  = (float*)d_ws;
  float* A   = ws;                      // 1024 floats
  float* WT  = ws + 1024;               // fc transposes (33408 f32) + conv2 pk (4608 u32) + conv1 pk (1024 u32)
  const unsigned* W2P = (const unsigned*)WT + 33408;
  const unsigned* W1P = (const unsigned*)WT + 38016;
  float* q   = ws + 43648;              // 262144 floats (1024x256)
  unsigned* h1p = (unsigned*)(ws + 305792);  // 8388608 u32 (1024 x 32pair x 16 x 16)
  float* h2  = ws + 17083008;           // 1048576 floats  (1024x16x8x8)

  k_qmat  <<<1,    256, 0, stream>>>(qw_u3, qw_ang, A);
  k_trans <<<167,  256, 0, stream>>>(fc1a_w, fc1b_w, fc2a_w, fc2b_w, conv2_w, conv1_w, conv1_b, WT);
  k_conv1 <<<2048, 256, 0, stream>>>(x, W1P, h1p);
  k_conv2 <<<2048, 256, 0, stream>>>(h1p, W2P, conv2_b, h2);
  k_conv3q<<<256,  256, 0, stream>>>(h2, conv3_w, conv3_b, A, q);
  k_fc    <<<256,  256, 0, stream>>>(q, WT, fc1a_b, fc1b_b, fc2a_b, fc2b_b, out);
}